// Round 2
// baseline (387.176 us; speedup 1.0000x reference)
//
#include <hip/hip_runtime.h>

#define BATCH 2048
#define NF 512
#define FD 64
#define SLOT (16 * 17 * 4)    // floats per wave slot: [kq=16][b=16+1pad][4]

// ============================================================================
// Layer-flat kernel: one block = (node, 64-row batch tile), 4 waves x 16 rows.
// Each wave: load 2 parent rows, elementwise product -> private LDS slot,
// then 64x64 matmul vs W (global, L1/L2-hot). NO __syncthreads anywhere:
// the slot is wave-private, ordering is wave-internal lgkmcnt only.
// Parent addr = child*pSA + row*pSB + tx*4 ; dest addr = node*oSA + row*oSB.
//   layer0: parents = in_graph  (pSA=FD,        pSB=NF*FD)
//   layerN: parents = ws buffer (pSA=BATCH*FD,  pSB=FD)
//   final : dest    = out       (oSA=FD,        oSB=8*FD)
// Exact same fmaf ordering as the previous fused kernel => absmax 0.0 kept.
// ============================================================================
__global__ __launch_bounds__(256) void layer_kernel(
    const float* __restrict__ parents,
    const float* __restrict__ weights,
    const int* __restrict__ fold_idx,
    const int* __restrict__ out_idx,
    float* __restrict__ dest,
    const int layer,
    const long pSA, const long pSB,
    const long oSA, const long oSB) {
  __shared__ float lds[4 * SLOT];   // 17408 B -> 8 blocks/CU

  const int node = blockIdx.x >> 5;     // 32 tiles of 64 rows = 2048 batch
  const int tile = blockIdx.x & 31;
  const int t  = threadIdx.x;
  const int w  = t >> 6;                // wave 0..3
  const int l  = t & 63;
  const int tx = l & 15;                // j-quad / k-quad lane
  const int ty = l >> 4;                // 0..3
  const int R0 = tile * 64 + w * 16;    // first batch row of this wave

  // ---- uniform (SGPR) fold chain: root -> this node's level-`layer` fold ----
  int f = out_idx[node >> (3 - layer)];
  #pragma unroll
  for (int L = 3; L > layer; --L)
    f = fold_idx[(L * NF + f) * 2 + ((node >> (L - 1 - layer)) & 1)];

  long c0, c1;
  if (layer == 0) {                     // children are in_graph folds
    c0 = fold_idx[f * 2 + 0];
    c1 = fold_idx[f * 2 + 1];
  } else {                              // children are previous-layer nodes
    c0 = 2 * node;
    c1 = 2 * node + 1;
  }

  float* slot = lds + w * SLOT;

  // ---- stage product h = p0 (.) p1 into the wave-private slot ----
  {
    const float* p0 = parents + c0 * pSA + tx * 4;
    const float* p1 = parents + c1 * pSA + tx * 4;
    #pragma unroll
    for (int r = 0; r < 4; ++r) {
      const int b = 4 * r + ty;
      const long row = (long)(R0 + b);
      float4 a = *(const float4*)(p0 + row * pSB);
      float4 c = *(const float4*)(p1 + row * pSB);
      float4 h;
      h.x = a.x * c.x; h.y = a.y * c.y; h.z = a.z * c.z; h.w = a.w * c.w;
      *(float4*)(slot + (tx * 17 + b) * 4) = h;
    }
  }
  // no barrier: same-wave LDS write->read ordered by lgkmcnt

  // ---- y = h @ W  (W from global; L1-shared by all 4 waves of the block) ----
  const float* W = weights + ((size_t)layer * NF + f) * (FD * FD);
  float4 acc[4];
  #pragma unroll
  for (int r = 0; r < 4; ++r) acc[r] = make_float4(0.f, 0.f, 0.f, 0.f);
  #pragma unroll 2
  for (int kq = 0; kq < 16; ++kq) {
    const float* Wk = W + kq * 4 * FD + tx * 4;
    float4 w0 = *(const float4*)(Wk);
    float4 w1 = *(const float4*)(Wk + FD);
    float4 w2 = *(const float4*)(Wk + 2 * FD);
    float4 w3 = *(const float4*)(Wk + 3 * FD);
    #pragma unroll
    for (int r = 0; r < 4; ++r) {
      float4 h = *(const float4*)(slot + (kq * 17 + 4 * r + ty) * 4);
      acc[r].x = fmaf(h.x, w0.x, acc[r].x); acc[r].y = fmaf(h.x, w0.y, acc[r].y);
      acc[r].z = fmaf(h.x, w0.z, acc[r].z); acc[r].w = fmaf(h.x, w0.w, acc[r].w);
      acc[r].x = fmaf(h.y, w1.x, acc[r].x); acc[r].y = fmaf(h.y, w1.y, acc[r].y);
      acc[r].z = fmaf(h.y, w1.z, acc[r].z); acc[r].w = fmaf(h.y, w1.w, acc[r].w);
      acc[r].x = fmaf(h.z, w2.x, acc[r].x); acc[r].y = fmaf(h.z, w2.y, acc[r].y);
      acc[r].z = fmaf(h.z, w2.z, acc[r].z); acc[r].w = fmaf(h.z, w2.w, acc[r].w);
      acc[r].x = fmaf(h.w, w3.x, acc[r].x); acc[r].y = fmaf(h.w, w3.y, acc[r].y);
      acc[r].z = fmaf(h.w, w3.z, acc[r].z); acc[r].w = fmaf(h.w, w3.w, acc[r].w);
    }
  }

  // ---- coalesced store ----
  #pragma unroll
  for (int r = 0; r < 4; ++r) {
    const long row = (long)(R0 + 4 * r + ty);
    *(float4*)(dest + node * oSA + row * oSB + tx * 4) = acc[r];
  }
}

// ============================================================================
// Fallback: previous fused in-block tree kernel (used only if ws too small).
// ============================================================================
#define BT 16
#define SLOTF (16 * 17 * 4)
__global__ __launch_bounds__(512) void fused_dag_kernel(
    const float* __restrict__ in_graph,
    const float* __restrict__ weights,
    const int* __restrict__ fold_idx,
    const int* __restrict__ out_idx,
    float* __restrict__ out) {
  __shared__ float bufA[8 * SLOTF];
  __shared__ float bufB[4 * SLOTF];
  __shared__ int T[32];

  const int o    = blockIdx.x & 7;
  const int tile = blockIdx.x >> 3;
  const int B0   = tile * BT;
  const int t    = threadIdx.x;

  if (t == 0) {
    int f4 = out_idx[o];
    T[0] = f4;
    T[1] = fold_idx[(3 * NF + f4) * 2 + 0];
    T[2] = fold_idx[(3 * NF + f4) * 2 + 1];
    #pragma unroll
    for (int i = 0; i < 2; ++i) {
      int f = T[1 + i];
      T[3 + 2 * i]     = fold_idx[(2 * NF + f) * 2 + 0];
      T[3 + 2 * i + 1] = fold_idx[(2 * NF + f) * 2 + 1];
    }
    #pragma unroll
    for (int i = 0; i < 4; ++i) {
      int f = T[3 + i];
      T[7 + 2 * i]     = fold_idx[(1 * NF + f) * 2 + 0];
      T[7 + 2 * i + 1] = fold_idx[(1 * NF + f) * 2 + 1];
    }
    #pragma unroll
    for (int i = 0; i < 8; ++i) {
      int f = T[7 + i];
      T[15 + 2 * i]     = fold_idx[(0 * NF + f) * 2 + 0];
      T[15 + 2 * i + 1] = fold_idx[(0 * NF + f) * 2 + 1];
    }
  }
  __syncthreads();

  const int w  = t >> 6;
  const int l  = t & 63;
  const int tx = l & 15;
  const int ty = l >> 4;

  {
    const int node = w;
    float* slot = bufA + node * SLOTF;
    const int f0 = T[15 + 2 * node];
    const int f1 = T[16 + 2 * node];
    #pragma unroll
    for (int r = 0; r < 4; ++r) {
      const int b = ty * 4 + r;
      const float* row = in_graph + (size_t)(B0 + b) * NF * FD + tx * 4;
      float4 a = *(const float4*)(row + f0 * FD);
      float4 c = *(const float4*)(row + f1 * FD);
      float4 h;
      h.x = a.x * c.x; h.y = a.y * c.y; h.z = a.z * c.z; h.w = a.w * c.w;
      *(float4*)(slot + (tx * 17 + b) * 4) = h;
    }
    const float* W = weights + (size_t)(0 * NF + T[7 + node]) * (FD * FD);
    float4 acc[4];
    #pragma unroll
    for (int r = 0; r < 4; ++r) acc[r] = make_float4(0.f, 0.f, 0.f, 0.f);
    #pragma unroll 2
    for (int kq = 0; kq < 16; ++kq) {
      const float* Wk = W + kq * 4 * FD + tx * 4;
      float4 w0 = *(const float4*)(Wk);
      float4 w1 = *(const float4*)(Wk + FD);
      float4 w2 = *(const float4*)(Wk + 2 * FD);
      float4 w3 = *(const float4*)(Wk + 3 * FD);
      #pragma unroll
      for (int r = 0; r < 4; ++r) {
        float4 h = *(const float4*)(slot + (kq * 17 + 4 * r + ty) * 4);
        acc[r].x = fmaf(h.x, w0.x, acc[r].x); acc[r].y = fmaf(h.x, w0.y, acc[r].y);
        acc[r].z = fmaf(h.x, w0.z, acc[r].z); acc[r].w = fmaf(h.x, w0.w, acc[r].w);
        acc[r].x = fmaf(h.y, w1.x, acc[r].x); acc[r].y = fmaf(h.y, w1.y, acc[r].y);
        acc[r].z = fmaf(h.y, w1.z, acc[r].z); acc[r].w = fmaf(h.y, w1.w, acc[r].w);
        acc[r].x = fmaf(h.z, w2.x, acc[r].x); acc[r].y = fmaf(h.z, w2.y, acc[r].y);
        acc[r].z = fmaf(h.z, w2.z, acc[r].z); acc[r].w = fmaf(h.z, w2.w, acc[r].w);
        acc[r].x = fmaf(h.w, w3.x, acc[r].x); acc[r].y = fmaf(h.w, w3.y, acc[r].y);
        acc[r].z = fmaf(h.w, w3.z, acc[r].z); acc[r].w = fmaf(h.w, w3.w, acc[r].w);
      }
    }
    #pragma unroll
    for (int r = 0; r < 4; ++r)
      *(float4*)(slot + (tx * 17 + 4 * r + ty) * 4) = acc[r];
  }
  __syncthreads();

  {
    const int node = w >> 1, half = w & 1;
    const float* P0 = bufA + (2 * node) * SLOTF;
    const float* P1 = bufA + (2 * node + 1) * SLOTF;
    const float* W = weights + (size_t)(1 * NF + T[3 + node]) * (FD * FD);
    float* slot = bufB + node * SLOTF;
    float4 acc[2];
    acc[0] = make_float4(0.f, 0.f, 0.f, 0.f);
    acc[1] = make_float4(0.f, 0.f, 0.f, 0.f);
    #pragma unroll 2
    for (int kq = 0; kq < 16; ++kq) {
      const float* Wk = W + kq * 4 * FD + tx * 4;
      float4 w0 = *(const float4*)(Wk);
      float4 w1 = *(const float4*)(Wk + FD);
      float4 w2 = *(const float4*)(Wk + 2 * FD);
      float4 w3 = *(const float4*)(Wk + 3 * FD);
      #pragma unroll
      for (int r = 0; r < 2; ++r) {
        const int b = half * 8 + 4 * r + ty;
        float4 pa = *(const float4*)(P0 + (kq * 17 + b) * 4);
        float4 pb = *(const float4*)(P1 + (kq * 17 + b) * 4);
        float4 h;
        h.x = pa.x * pb.x; h.y = pa.y * pb.y; h.z = pa.z * pb.z; h.w = pa.w * pb.w;
        acc[r].x = fmaf(h.x, w0.x, acc[r].x); acc[r].y = fmaf(h.x, w0.y, acc[r].y);
        acc[r].z = fmaf(h.x, w0.z, acc[r].z); acc[r].w = fmaf(h.x, w0.w, acc[r].w);
        acc[r].x = fmaf(h.y, w1.x, acc[r].x); acc[r].y = fmaf(h.y, w1.y, acc[r].y);
        acc[r].z = fmaf(h.y, w1.z, acc[r].z); acc[r].w = fmaf(h.y, w1.w, acc[r].w);
        acc[r].x = fmaf(h.z, w2.x, acc[r].x); acc[r].y = fmaf(h.z, w2.y, acc[r].y);
        acc[r].z = fmaf(h.z, w2.z, acc[r].z); acc[r].w = fmaf(h.z, w2.w, acc[r].w);
        acc[r].x = fmaf(h.w, w3.x, acc[r].x); acc[r].y = fmaf(h.w, w3.y, acc[r].y);
        acc[r].z = fmaf(h.w, w3.z, acc[r].z); acc[r].w = fmaf(h.w, w3.w, acc[r].w);
      }
    }
    #pragma unroll
    for (int r = 0; r < 2; ++r)
      *(float4*)(slot + (tx * 17 + half * 8 + 4 * r + ty) * 4) = acc[r];
  }
  __syncthreads();

  {
    const int node = w >> 2, q = w & 3;
    const float* P0 = bufB + (2 * node) * SLOTF;
    const float* P1 = bufB + (2 * node + 1) * SLOTF;
    const float* W = weights + (size_t)(2 * NF + T[1 + node]) * (FD * FD);
    float* slot = bufA + node * SLOTF;
    const int b = q * 4 + ty;
    float4 acc = make_float4(0.f, 0.f, 0.f, 0.f);
    #pragma unroll 2
    for (int kq = 0; kq < 16; ++kq) {
      const float* Wk = W + kq * 4 * FD + tx * 4;
      float4 w0 = *(const float4*)(Wk);
      float4 w1 = *(const float4*)(Wk + FD);
      float4 w2 = *(const float4*)(Wk + 2 * FD);
      float4 w3 = *(const float4*)(Wk + 3 * FD);
      float4 pa = *(const float4*)(P0 + (kq * 17 + b) * 4);
      float4 pb = *(const float4*)(P1 + (kq * 17 + b) * 4);
      float4 h;
      h.x = pa.x * pb.x; h.y = pa.y * pb.y; h.z = pa.z * pb.z; h.w = pa.w * pb.w;
      acc.x = fmaf(h.x, w0.x, acc.x); acc.y = fmaf(h.x, w0.y, acc.y);
      acc.z = fmaf(h.x, w0.z, acc.z); acc.w = fmaf(h.x, w0.w, acc.w);
      acc.x = fmaf(h.y, w1.x, acc.x); acc.y = fmaf(h.y, w1.y, acc.y);
      acc.z = fmaf(h.y, w1.z, acc.z); acc.w = fmaf(h.y, w1.w, acc.w);
      acc.x = fmaf(h.z, w2.x, acc.x); acc.y = fmaf(h.z, w2.y, acc.y);
      acc.z = fmaf(h.z, w2.z, acc.z); acc.w = fmaf(h.z, w2.w, acc.w);
      acc.x = fmaf(h.w, w3.x, acc.x); acc.y = fmaf(h.w, w3.y, acc.y);
      acc.z = fmaf(h.w, w3.z, acc.z); acc.w = fmaf(h.w, w3.w, acc.w);
    }
    *(float4*)(slot + (tx * 17 + b) * 4) = acc;
  }
  __syncthreads();

  if (w < 4) {
    const float* P0 = bufA + 0 * SLOTF;
    const float* P1 = bufA + 1 * SLOTF;
    const float* W = weights + (size_t)(3 * NF + T[0]) * (FD * FD);
    const int b = w * 4 + ty;
    float4 acc = make_float4(0.f, 0.f, 0.f, 0.f);
    #pragma unroll 2
    for (int kq = 0; kq < 16; ++kq) {
      const float* Wk = W + kq * 4 * FD + tx * 4;
      float4 w0 = *(const float4*)(Wk);
      float4 w1 = *(const float4*)(Wk + FD);
      float4 w2 = *(const float4*)(Wk + 2 * FD);
      float4 w3 = *(const float4*)(Wk + 3 * FD);
      float4 pa = *(const float4*)(P0 + (kq * 17 + b) * 4);
      float4 pb = *(const float4*)(P1 + (kq * 17 + b) * 4);
      float4 h;
      h.x = pa.x * pb.x; h.y = pa.y * pb.y; h.z = pa.z * pb.z; h.w = pa.w * pb.w;
      acc.x = fmaf(h.x, w0.x, acc.x); acc.y = fmaf(h.x, w0.y, acc.y);
      acc.z = fmaf(h.x, w0.z, acc.z); acc.w = fmaf(h.x, w0.w, acc.w);
      acc.x = fmaf(h.y, w1.x, acc.x); acc.y = fmaf(h.y, w1.y, acc.y);
      acc.z = fmaf(h.y, w1.z, acc.z); acc.w = fmaf(h.y, w1.w, acc.w);
      acc.x = fmaf(h.z, w2.x, acc.x); acc.y = fmaf(h.z, w2.y, acc.y);
      acc.z = fmaf(h.z, w2.z, acc.z); acc.w = fmaf(h.z, w2.w, acc.w);
      acc.x = fmaf(h.w, w3.x, acc.x); acc.y = fmaf(h.w, w3.y, acc.y);
      acc.z = fmaf(h.w, w3.z, acc.z); acc.w = fmaf(h.w, w3.w, acc.w);
    }
    *(float4*)(out + ((size_t)(B0 + b) * 8 + o) * FD + tx * 4) = acc;
  }
}

extern "C" void kernel_launch(void* const* d_in, const int* in_sizes, int n_in,
                              void* d_out, int out_size, void* d_ws, size_t ws_size,
                              hipStream_t stream) {
  const float* in_graph = (const float*)d_in[0];
  const float* weights  = (const float*)d_in[1];
  const int*   fold_idx = (const int*)d_in[2];
  const int*   out_idx  = (const int*)d_in[3];
  float* out = (float*)d_out;

  const size_t nodeF = (size_t)BATCH * FD;                 // floats per node buf
  const size_t need  = (64 + 32) * nodeF * sizeof(float);  // 48 MB ping-pong

  if (ws_size >= need) {
    float* b0 = (float*)d_ws;            // 64-node buffer (32 MB), reused for L2
    float* b1 = b0 + 64 * nodeF;         // 32-node buffer (16 MB)
    const long NB = (long)nodeF;         // 131072
    // layer 0: in_graph -> b0   (parents fold-indexed inside batch rows)
    layer_kernel<<<64 * 32, 256, 0, stream>>>(in_graph, weights, fold_idx, out_idx,
        b0, 0, (long)FD, (long)NF * FD, NB, (long)FD);
    // layer 1: b0 -> b1
    layer_kernel<<<32 * 32, 256, 0, stream>>>(b0, weights, fold_idx, out_idx,
        b1, 1, NB, (long)FD, NB, (long)FD);
    // layer 2: b1 -> b0 (region dead after layer 1 consumed it)
    layer_kernel<<<16 * 32, 256, 0, stream>>>(b1, weights, fold_idx, out_idx,
        b0, 2, NB, (long)FD, NB, (long)FD);
    // layer 3: b0 -> out[b][o][j]
    layer_kernel<<<8 * 32, 256, 0, stream>>>(b0, weights, fold_idx, out_idx,
        out, 3, NB, (long)FD, (long)FD, (long)(8 * FD));
  } else {
    fused_dag_kernel<<<(BATCH / BT) * 8, 512, 0, stream>>>(
        in_graph, weights, fold_idx, out_idx, out);
  }
}